// Round 1
// baseline (2070.354 us; speedup 1.0000x reference)
//
#include <hip/hip_runtime.h>

#define NS    8
#define HGT   128
#define WID   128
#define HW    (HGT * WID)      // 16384 = 2^14
#define BATCH 32
#define EPSV  1e-8f
#define ITERS 20

// tile config for the smooth kernels: 32 wide (full 128B lines) x 8 tall
#define TW   32
#define TH   8
#define HALO 2
#define LW   (TW + 2 * HALO)   // 36
#define LH   (TH + 2 * HALO)   // 12

// Prologue: H0 = exp(logH)  (stored in d_out as scratch), u = v = 1,
// m_row[b,i,p] = sum_j H0[b,i,j,p]   (since u=v=1 initially).
__global__ void k_init(const float* __restrict__ logH, float* __restrict__ H0,
                       float* __restrict__ u, float* __restrict__ v,
                       float* __restrict__ mrow) {
    int gid = blockIdx.x * 256 + threadIdx.x;   // over B*NS*HW = 4,194,304
    int p = gid & (HW - 1);
    int c = (gid >> 14) & 7;
    int b = gid >> 17;
    int base = ((b * NS + c) * NS) * HW + p;
    float s = 0.f;
#pragma unroll
    for (int j = 0; j < NS; ++j) {
        float e = expf(logH[base + j * HW]);
        H0[base + j * HW] = e;
        s += e;
    }
    u[gid] = 1.f;
    v[gid] = 1.f;
    mrow[gid] = s;
}

// One Sinkhorn half-step, fused:
//   a[c] /= (smooth(m_in)[c] + eps)          (a = u for row-step, v for col-step)
//   if (emit) m_out[c'] = bvec[c'] * sum_c M[sel]*a[c]   (the *other* marginal)
// ROWSTEP=1: a=u (indexed by i), emit over j with M[i][j] -> channel i*8+j
// ROWSTEP=0: a=v (indexed by j), emit over i with M[i][j] -> channel i*8+j (cp*8+c)
template <int ROWSTEP>
__global__ void k_step(const float* __restrict__ m_in,
                       float* __restrict__ a,
                       const float* __restrict__ bvec,
                       float* __restrict__ m_out,
                       const float* __restrict__ H0,
                       const float* __restrict__ gk,
                       int emit) {
    __shared__ float tile[NS][LH][LW];
    __shared__ float wk[25];
    int tid = threadIdx.x;
    if (tid < 25) wk[tid] = gk[tid];
    int b   = blockIdx.z;
    int ty0 = blockIdx.y * TH;
    int tx0 = blockIdx.x * TW;

    // cooperative halo load (circular wrap) for all 8 channels
    const int LSZ = LH * LW;  // 432
#pragma unroll
    for (int c = 0; c < NS; ++c) {
        const float* src = m_in + (b * NS + c) * HW;
        for (int t = tid; t < LSZ; t += 256) {
            int ly = t / LW, lx = t - ly * LW;
            int gh = (ty0 + ly - HALO + HGT) & (HGT - 1);
            int gw = (tx0 + lx - HALO + WID) & (WID - 1);
            tile[c][ly][lx] = src[gh * WID + gw];
        }
    }
    __syncthreads();

    int lx = tid & (TW - 1);
    int ly = tid >> 5;
    int p = (ty0 + ly) * WID + (tx0 + lx);

    float av[NS];
#pragma unroll
    for (int c = 0; c < NS; ++c) {
        float s = 0.f;
#pragma unroll
        for (int dy = 0; dy < 5; ++dy)
#pragma unroll
            for (int dx = 0; dx < 5; ++dx)
                s += wk[dy * 5 + dx] * tile[c][ly + dy][lx + dx];
        int ai = (b * NS + c) * HW + p;
        float un = a[ai] / (s + EPSV);
        a[ai] = un;
        av[c] = un;
    }

    if (emit) {
        float acc[NS];
#pragma unroll
        for (int cp = 0; cp < NS; ++cp) acc[cp] = 0.f;
        const float* Hb = H0 + b * NS * NS * HW + p;
#pragma unroll
        for (int c = 0; c < NS; ++c) {
            float x = av[c];
#pragma unroll
            for (int cp = 0; cp < NS; ++cp) {
                int ch = ROWSTEP ? (c * NS + cp) : (cp * NS + c);
                acc[cp] += Hb[ch * HW] * x;
            }
        }
#pragma unroll
        for (int cp = 0; cp < NS; ++cp) {
            int oi = (b * NS + cp) * HW + p;
            m_out[oi] = bvec[oi] * acc[cp];
        }
    }
}

// Epilogue: out = H0 * u * v + eps, in place on d_out (which holds H0).
__global__ void k_final(float* __restrict__ H0, const float* __restrict__ u,
                        const float* __restrict__ v) {
    int gid = blockIdx.x * 256 + threadIdx.x;  // over total/4
    int e = gid * 4;
    int p  = e & (HW - 1);
    int cj = (e >> 14) & 7;
    int ci = (e >> 17) & 7;
    int b  = e >> 20;
    float4 h  = *(const float4*)(H0 + e);
    float4 uu = *(const float4*)(u + (b * NS + ci) * HW + p);
    float4 vv = *(const float4*)(v + (b * NS + cj) * HW + p);
    h.x = h.x * uu.x * vv.x + EPSV;
    h.y = h.y * uu.y * vv.y + EPSV;
    h.z = h.z * uu.z * vv.z + EPSV;
    h.w = h.w * uu.w * vv.w + EPSV;
    *(float4*)(H0 + e) = h;
}

extern "C" void kernel_launch(void* const* d_in, const int* in_sizes, int n_in,
                              void* d_out, int out_size, void* d_ws, size_t ws_size,
                              hipStream_t stream) {
    const float* logH = (const float*)d_in[0];
    const float* gk   = (const float*)d_in[1];
    float* H0 = (float*)d_out;                 // 33,554,432 floats (scratch + final out)
    float* ws = (float*)d_ws;
    const int VEC = BATCH * NS * HW;           // 4,194,304
    float* u    = ws;
    float* v    = ws + VEC;
    float* mrow = ws + 2 * VEC;
    float* mcol = ws + 3 * VEC;                // needs 67.1 MB of d_ws

    k_init<<<VEC / 256, 256, 0, stream>>>(logH, H0, u, v, mrow);

    dim3 grid(WID / TW, HGT / TH, BATCH);      // 4 x 16 x 32 = 2048 blocks
    for (int it = 0; it < ITERS; ++it) {
        // row step: update u from smooth(mrow), emit mcol = v .* (M^T u)
        k_step<1><<<grid, 256, 0, stream>>>(mrow, u, v, mcol, H0, gk, 1);
        // col step: update v from smooth(mcol), emit mrow = u .* (M v)
        k_step<0><<<grid, 256, 0, stream>>>(mcol, v, u, mrow, H0, gk,
                                            it != ITERS - 1 ? 1 : 0);
    }

    int total4 = BATCH * NS * NS * HW / 4;     // 8,388,608
    k_final<<<total4 / 256, 256, 0, stream>>>(H0, u, v);
}

// Round 2
// 1899.245 us; speedup vs baseline: 1.0901x; 1.0901x over previous
//
#include <hip/hip_runtime.h>

#define NS    8
#define HGT   128
#define WID   128
#define HW    (HGT * WID)      // 16384
#define BATCH 32
#define EPSV  1e-8f
#define ITERS 20

// full-row tiles: 128 wide x 8 tall, 256 threads x 4 pixels each
#define TH   8
#define LH   (TH + 4)          // 12 rows (halo 2 each side)
#define LW   132               // 128 + 2 halo each side

typedef float4 f4;

// ---------------------------------------------------------------------------
// Prologue: H0 = exp(logH) (into d_out as scratch), u = v = 1,
// mrow[b,i,p] = sum_j H0[b,i,j,p]  (u=v=1 initially). 4 px/thread.
__global__ __launch_bounds__(256) void k_init(const float* __restrict__ logH,
                                              float* __restrict__ H0,
                                              float* __restrict__ u,
                                              float* __restrict__ v,
                                              float* __restrict__ mrow) {
    int gid = blockIdx.x * 256 + threadIdx.x;   // over VEC/4 = 1,048,576
    int e = gid * 4;
    int p = e & (HW - 1);
    int c = (e >> 14) & 7;
    int b = e >> 17;
    int base = ((b * NS + c) * NS) * HW + p;
    f4 s = {0.f, 0.f, 0.f, 0.f};
#pragma unroll
    for (int j = 0; j < NS; ++j) {
        f4 l = *(const f4*)(logH + base + j * HW);
        f4 ev;
        ev.x = __expf(l.x); ev.y = __expf(l.y);
        ev.z = __expf(l.z); ev.w = __expf(l.w);
        *(f4*)(H0 + base + j * HW) = ev;
        s.x += ev.x; s.y += ev.y; s.z += ev.z; s.w += ev.w;
    }
    f4 one = {1.f, 1.f, 1.f, 1.f};
    *(f4*)(u + e) = one;
    *(f4*)(v + e) = one;
    *(f4*)(mrow + e) = s;
}

// ---------------------------------------------------------------------------
// Shared helper: stage 8-channel tile of m_in (12 rows x 132 cols, circular)
// and compute the 5x5 conv + divide for this thread's 4 pixels.
// Returns av[c] (the updated scale vector values) and writes them to a[] if
// WRITE_A. Layout: lxq = tid&31 (x-quad), ly = tid>>5 (row in tile).
__device__ __forceinline__ void stage_and_smooth(
        const float* __restrict__ m_in, const float* __restrict__ gk,
        float* __restrict__ a, int b, int ty0, int tid,
        float tile[NS][LH][LW], float wk[25], f4 av[NS], bool write_a) {
    if (tid < 25) wk[tid] = gk[tid];

    // main body: per channel 12 rows x 32 f4
#pragma unroll
    for (int c = 0; c < NS; ++c) {
        const float* src = m_in + (b * NS + c) * HW;
        for (int t = tid; t < LH * 32; t += 256) {
            int ly = t >> 5, lxq = t & 31;
            int gh = (ty0 + ly - 2 + HGT) & (HGT - 1);
            f4 val = *(const f4*)(src + gh * WID + lxq * 4);
            float* dst = &tile[c][ly][2 + lxq * 4];
            dst[0] = val.x; dst[1] = val.y; dst[2] = val.z; dst[3] = val.w;
        }
        // edge columns: hx 0,1 <- x 126,127 ; hx 130,131 <- x 0,1
        if (tid < LH * 4) {
            int ly = tid >> 2, e = tid & 3;
            int gh = (ty0 + ly - 2 + HGT) & (HGT - 1);
            int x  = (e < 2) ? (126 + e) : (e - 2);
            int hx = (e < 2) ? e : (128 + e);
            tile[c][ly][hx] = src[gh * WID + x];
        }
    }
    __syncthreads();

    int lxq = tid & 31;
    int ly  = tid >> 5;
    int p   = (ty0 + ly) * WID + lxq * 4;

#pragma unroll
    for (int c = 0; c < NS; ++c) {
        float s0 = 0.f, s1 = 0.f, s2 = 0.f, s3 = 0.f;
#pragma unroll
        for (int dy = 0; dy < 5; ++dy) {
            const float* row = &tile[c][ly + dy][lxq * 4];  // 16B aligned
            f4 A = *(const f4*)row;
            f4 B = *(const f4*)(row + 4);
            float vv[8] = {A.x, A.y, A.z, A.w, B.x, B.y, B.z, B.w};
#pragma unroll
            for (int dx = 0; dx < 5; ++dx) {
                float w = wk[dy * 5 + dx];
                s0 += w * vv[dx];
                s1 += w * vv[dx + 1];
                s2 += w * vv[dx + 2];
                s3 += w * vv[dx + 3];
            }
        }
        int ai = (b * NS + c) * HW + p;
        f4 ao = *(const f4*)(a + ai);
        f4 un;
        un.x = ao.x / (s0 + EPSV);
        un.y = ao.y / (s1 + EPSV);
        un.z = ao.z / (s2 + EPSV);
        un.w = ao.w / (s3 + EPSV);
        if (write_a) *(f4*)(a + ai) = un;
        av[c] = un;
    }
}

// ---------------------------------------------------------------------------
// One Sinkhorn half-step: a /= (smooth(m_in)+eps); emit the other marginal
// m_out[c'] = bvec[c'] * sum_c H0[sel] * a[c].
// ROWSTEP=1: a=u (i), emit over j, channel i*8+j. ROWSTEP=0: a=v (j), ch cp*8+c.
template <int ROWSTEP>
__global__ __launch_bounds__(256) void k_step(const float* __restrict__ m_in,
                                              float* __restrict__ a,
                                              const float* __restrict__ bvec,
                                              float* __restrict__ m_out,
                                              const float* __restrict__ H0,
                                              const float* __restrict__ gk) {
    __shared__ float tile[NS][LH][LW];
    __shared__ float wk[25];
    int tid = threadIdx.x;
    int b   = blockIdx.z;
    int ty0 = blockIdx.y * TH;

    f4 av[NS];
    stage_and_smooth(m_in, gk, a, b, ty0, tid, tile, wk, av, true);

    int lxq = tid & 31;
    int ly  = tid >> 5;
    int p   = (ty0 + ly) * WID + lxq * 4;

    f4 acc[NS];
#pragma unroll
    for (int cp = 0; cp < NS; ++cp) acc[cp] = f4{0.f, 0.f, 0.f, 0.f};
    const float* Hb = H0 + b * NS * NS * HW + p;
#pragma unroll
    for (int c = 0; c < NS; ++c) {
        f4 x = av[c];
#pragma unroll
        for (int cp = 0; cp < NS; ++cp) {
            int ch = ROWSTEP ? (c * NS + cp) : (cp * NS + c);
            f4 h = *(const f4*)(Hb + ch * HW);
            acc[cp].x += h.x * x.x;
            acc[cp].y += h.y * x.y;
            acc[cp].z += h.z * x.z;
            acc[cp].w += h.w * x.w;
        }
    }
#pragma unroll
    for (int cp = 0; cp < NS; ++cp) {
        int oi = (b * NS + cp) * HW + p;
        f4 bv = *(const f4*)(bvec + oi);
        f4 o;
        o.x = bv.x * acc[cp].x;
        o.y = bv.y * acc[cp].y;
        o.z = bv.z * acc[cp].z;
        o.w = bv.w * acc[cp].w;
        *(f4*)(m_out + oi) = o;
    }
}

// ---------------------------------------------------------------------------
// Last col-step fused with epilogue: vnew = v/(smooth(mcol)+eps) (not stored),
// out[b,i,j,p] = H0[b,i,j,p] * u[b,i,p] * vnew[b,j,p] + eps   (in place on H0).
__global__ __launch_bounds__(256) void k_last(const float* __restrict__ m_in,
                                              float* __restrict__ v,
                                              const float* __restrict__ u,
                                              float* __restrict__ H0,
                                              const float* __restrict__ gk) {
    __shared__ float tile[NS][LH][LW];
    __shared__ float wk[25];
    int tid = threadIdx.x;
    int b   = blockIdx.z;
    int ty0 = blockIdx.y * TH;

    f4 av[NS];   // vnew[j]
    stage_and_smooth(m_in, gk, v, b, ty0, tid, tile, wk, av, false);

    int lxq = tid & 31;
    int ly  = tid >> 5;
    int p   = (ty0 + ly) * WID + lxq * 4;

    float* Hb = H0 + b * NS * NS * HW + p;
#pragma unroll
    for (int i = 0; i < NS; ++i) {
        f4 uu = *(const f4*)(u + (b * NS + i) * HW + p);
#pragma unroll
        for (int j = 0; j < NS; ++j) {
            f4 h = *(const f4*)(Hb + (i * NS + j) * HW);
            f4 o;
            o.x = h.x * uu.x * av[j].x + EPSV;
            o.y = h.y * uu.y * av[j].y + EPSV;
            o.z = h.z * uu.z * av[j].z + EPSV;
            o.w = h.w * uu.w * av[j].w + EPSV;
            *(f4*)(Hb + (i * NS + j) * HW) = o;
        }
    }
}

extern "C" void kernel_launch(void* const* d_in, const int* in_sizes, int n_in,
                              void* d_out, int out_size, void* d_ws, size_t ws_size,
                              hipStream_t stream) {
    const float* logH = (const float*)d_in[0];
    const float* gk   = (const float*)d_in[1];
    float* H0 = (float*)d_out;                 // scratch holding exp(logH), then final out
    float* ws = (float*)d_ws;
    const int VEC = BATCH * NS * HW;           // 4,194,304
    float* u    = ws;
    float* v    = ws + VEC;
    float* mrow = ws + 2 * VEC;
    float* mcol = ws + 3 * VEC;

    k_init<<<VEC / 4 / 256, 256, 0, stream>>>(logH, H0, u, v, mrow);

    dim3 grid(1, HGT / TH, BATCH);             // 1 x 16 x 32 = 512 blocks
    for (int it = 0; it < ITERS; ++it) {
        // row step: u /= smooth(mrow)+eps; emit mcol = v .* (M^T u)
        k_step<1><<<grid, 256, 0, stream>>>(mrow, u, v, mcol, H0, gk);
        if (it != ITERS - 1) {
            // col step: v /= smooth(mcol)+eps; emit mrow = u .* (M v)
            k_step<0><<<grid, 256, 0, stream>>>(mcol, v, u, mrow, H0, gk);
        } else {
            // fused last col step + epilogue (writes final output into H0)
            k_last<<<grid, 256, 0, stream>>>(mcol, v, u, H0, gk);
        }
    }
}

// Round 3
// 1474.510 us; speedup vs baseline: 1.4041x; 1.2881x over previous
//
#include <hip/hip_runtime.h>

#define NS    8
#define HGT   128
#define WID   128
#define HW    (HGT * WID)      // 16384
#define BATCH 32
#define EPSV  1e-8f
#define ITERS 20

// full-row tiles: 128 wide x 8 tall, 256 threads x 4 pixels each
#define TH   8
#define LH   (TH + 4)          // 12 rows (halo 2 each side)
#define LW   132               // 128 + 2 halo each side

typedef float4 f4;
typedef _Float16 half4 __attribute__((ext_vector_type(4)));

// ---------------------------------------------------------------------------
// Prologue: H0h = fp16(exp(logH)) (into d_out as scratch), u = v = 1,
// mrow[b,i,p] = sum_j exp(logH)[b,i,j,p]  (u=v=1 initially). 4 px/thread.
__global__ __launch_bounds__(256) void k_init(const float* __restrict__ logH,
                                              _Float16* __restrict__ H0h,
                                              float* __restrict__ u,
                                              float* __restrict__ v,
                                              float* __restrict__ mrow) {
    int gid = blockIdx.x * 256 + threadIdx.x;   // over VEC/4 = 1,048,576
    int e = gid * 4;
    int p = e & (HW - 1);
    int c = (e >> 14) & 7;
    int b = e >> 17;
    int base = ((b * NS + c) * NS) * HW + p;
    f4 s = {0.f, 0.f, 0.f, 0.f};
#pragma unroll
    for (int j = 0; j < NS; ++j) {
        f4 l = *(const f4*)(logH + base + j * HW);
        f4 ev;
        ev.x = __expf(l.x); ev.y = __expf(l.y);
        ev.z = __expf(l.z); ev.w = __expf(l.w);
        half4 h;
        h.x = (_Float16)ev.x; h.y = (_Float16)ev.y;
        h.z = (_Float16)ev.z; h.w = (_Float16)ev.w;
        *(half4*)(H0h + base + j * HW) = h;
        s.x += ev.x; s.y += ev.y; s.z += ev.z; s.w += ev.w;
    }
    f4 one = {1.f, 1.f, 1.f, 1.f};
    *(f4*)(u + e) = one;
    *(f4*)(v + e) = one;
    *(f4*)(mrow + e) = s;
}

// ---------------------------------------------------------------------------
// Shared helper: stage 8-channel tile of m_in (12 rows x 132 cols, circular)
// and compute the 5x5 conv + divide for this thread's 4 pixels.
__device__ __forceinline__ void stage_and_smooth(
        const float* __restrict__ m_in, const float* __restrict__ gk,
        float* __restrict__ a, int b, int ty0, int tid,
        float tile[NS][LH][LW], float wk[25], f4 av[NS], bool write_a) {
    if (tid < 25) wk[tid] = gk[tid];

    // main body: per channel 12 rows x 32 f4
#pragma unroll
    for (int c = 0; c < NS; ++c) {
        const float* src = m_in + (b * NS + c) * HW;
        for (int t = tid; t < LH * 32; t += 256) {
            int ly = t >> 5, lxq = t & 31;
            int gh = (ty0 + ly - 2 + HGT) & (HGT - 1);
            f4 val = *(const f4*)(src + gh * WID + lxq * 4);
            float* dst = &tile[c][ly][2 + lxq * 4];
            dst[0] = val.x; dst[1] = val.y; dst[2] = val.z; dst[3] = val.w;
        }
        // edge columns: hx 0,1 <- x 126,127 ; hx 130,131 <- x 0,1
        if (tid < LH * 4) {
            int ly = tid >> 2, e = tid & 3;
            int gh = (ty0 + ly - 2 + HGT) & (HGT - 1);
            int x  = (e < 2) ? (126 + e) : (e - 2);
            int hx = (e < 2) ? e : (128 + e);
            tile[c][ly][hx] = src[gh * WID + x];
        }
    }
    __syncthreads();

    int lxq = tid & 31;
    int ly  = tid >> 5;
    int p   = (ty0 + ly) * WID + lxq * 4;

#pragma unroll
    for (int c = 0; c < NS; ++c) {
        float s0 = 0.f, s1 = 0.f, s2 = 0.f, s3 = 0.f;
#pragma unroll
        for (int dy = 0; dy < 5; ++dy) {
            const float* row = &tile[c][ly + dy][lxq * 4];  // 16B aligned
            f4 A = *(const f4*)row;
            f4 B = *(const f4*)(row + 4);
            float vv[8] = {A.x, A.y, A.z, A.w, B.x, B.y, B.z, B.w};
#pragma unroll
            for (int dx = 0; dx < 5; ++dx) {
                float w = wk[dy * 5 + dx];
                s0 += w * vv[dx];
                s1 += w * vv[dx + 1];
                s2 += w * vv[dx + 2];
                s3 += w * vv[dx + 3];
            }
        }
        int ai = (b * NS + c) * HW + p;
        f4 ao = *(const f4*)(a + ai);
        f4 un;
        un.x = ao.x / (s0 + EPSV);
        un.y = ao.y / (s1 + EPSV);
        un.z = ao.z / (s2 + EPSV);
        un.w = ao.w / (s3 + EPSV);
        if (write_a) *(f4*)(a + ai) = un;
        av[c] = un;
    }
}

// ---------------------------------------------------------------------------
// One Sinkhorn half-step: a /= (smooth(m_in)+eps); emit the other marginal
// m_out[c'] = bvec[c'] * sum_c H0h[sel] * a[c]   (H0h in fp16).
// ROWSTEP=1: a=u (i), emit over j, channel i*8+j. ROWSTEP=0: a=v (j), ch cp*8+c.
template <int ROWSTEP>
__global__ __launch_bounds__(256) void k_step(const float* __restrict__ m_in,
                                              float* __restrict__ a,
                                              const float* __restrict__ bvec,
                                              float* __restrict__ m_out,
                                              const _Float16* __restrict__ H0h,
                                              const float* __restrict__ gk) {
    __shared__ float tile[NS][LH][LW];
    __shared__ float wk[25];
    int tid = threadIdx.x;
    int b   = blockIdx.z;
    int ty0 = blockIdx.y * TH;

    f4 av[NS];
    stage_and_smooth(m_in, gk, a, b, ty0, tid, tile, wk, av, true);

    int lxq = tid & 31;
    int ly  = tid >> 5;
    int p   = (ty0 + ly) * WID + lxq * 4;

    f4 acc[NS];
#pragma unroll
    for (int cp = 0; cp < NS; ++cp) acc[cp] = f4{0.f, 0.f, 0.f, 0.f};
    const _Float16* Hb = H0h + b * NS * NS * HW + p;
#pragma unroll
    for (int c = 0; c < NS; ++c) {
        f4 x = av[c];
#pragma unroll
        for (int cp = 0; cp < NS; ++cp) {
            int ch = ROWSTEP ? (c * NS + cp) : (cp * NS + c);
            half4 h = *(const half4*)(Hb + ch * HW);
            acc[cp].x += (float)h.x * x.x;
            acc[cp].y += (float)h.y * x.y;
            acc[cp].z += (float)h.z * x.z;
            acc[cp].w += (float)h.w * x.w;
        }
    }
#pragma unroll
    for (int cp = 0; cp < NS; ++cp) {
        int oi = (b * NS + cp) * HW + p;
        f4 bv = *(const f4*)(bvec + oi);
        f4 o;
        o.x = bv.x * acc[cp].x;
        o.y = bv.y * acc[cp].y;
        o.z = bv.z * acc[cp].z;
        o.w = bv.w * acc[cp].w;
        *(f4*)(m_out + oi) = o;
    }
}

// ---------------------------------------------------------------------------
// Last col-step fused with epilogue: vnew = v/(smooth(mcol)+eps) (not stored),
// out[b,i,j,p] = exp(logH)[b,i,j,p] * u[b,i,p] * vnew[b,j,p] + eps.
// Recomputes exp from pristine logH in full fp32 (overwrites the fp16 H0h
// scratch living in d_out — never read here, so no hazard).
__global__ __launch_bounds__(256) void k_last(const float* __restrict__ m_in,
                                              float* __restrict__ v,
                                              const float* __restrict__ u,
                                              const float* __restrict__ logH,
                                              float* __restrict__ out,
                                              const float* __restrict__ gk) {
    __shared__ float tile[NS][LH][LW];
    __shared__ float wk[25];
    int tid = threadIdx.x;
    int b   = blockIdx.z;
    int ty0 = blockIdx.y * TH;

    f4 av[NS];   // vnew[j]
    stage_and_smooth(m_in, gk, v, b, ty0, tid, tile, wk, av, false);

    int lxq = tid & 31;
    int ly  = tid >> 5;
    int p   = (ty0 + ly) * WID + lxq * 4;

    const float* Lb = logH + b * NS * NS * HW + p;
    float* Ob = out + b * NS * NS * HW + p;
#pragma unroll
    for (int i = 0; i < NS; ++i) {
        f4 uu = *(const f4*)(u + (b * NS + i) * HW + p);
#pragma unroll
        for (int j = 0; j < NS; ++j) {
            f4 l = *(const f4*)(Lb + (i * NS + j) * HW);
            f4 o;
            o.x = expf(l.x) * uu.x * av[j].x + EPSV;
            o.y = expf(l.y) * uu.y * av[j].y + EPSV;
            o.z = expf(l.z) * uu.z * av[j].z + EPSV;
            o.w = expf(l.w) * uu.w * av[j].w + EPSV;
            *(f4*)(Ob + (i * NS + j) * HW) = o;
        }
    }
}

extern "C" void kernel_launch(void* const* d_in, const int* in_sizes, int n_in,
                              void* d_out, int out_size, void* d_ws, size_t ws_size,
                              hipStream_t stream) {
    const float* logH = (const float*)d_in[0];
    const float* gk   = (const float*)d_in[1];
    float* out = (float*)d_out;                 // final output; front half is H0h scratch
    _Float16* H0h = (_Float16*)d_out;           // 67 MB fp16 scratch inside d_out
    float* ws = (float*)d_ws;
    const int VEC = BATCH * NS * HW;            // 4,194,304
    float* u    = ws;
    float* v    = ws + VEC;
    float* mrow = ws + 2 * VEC;
    float* mcol = ws + 3 * VEC;                 // d_ws usage: 67 MB

    k_init<<<VEC / 4 / 256, 256, 0, stream>>>(logH, H0h, u, v, mrow);

    dim3 grid(1, HGT / TH, BATCH);              // 1 x 16 x 32 = 512 blocks
    for (int it = 0; it < ITERS; ++it) {
        // row step: u /= smooth(mrow)+eps; emit mcol = v .* (M^T u)
        k_step<1><<<grid, 256, 0, stream>>>(mrow, u, v, mcol, H0h, gk);
        if (it != ITERS - 1) {
            // col step: v /= smooth(mcol)+eps; emit mrow = u .* (M v)
            k_step<0><<<grid, 256, 0, stream>>>(mcol, v, u, mrow, H0h, gk);
        } else {
            // fused last col step + epilogue (fp32 exp recompute, final write)
            k_last<<<grid, 256, 0, stream>>>(mcol, v, u, logH, out, gk);
        }
    }
}